// Round 3
// baseline (765.580 us; speedup 1.0000x reference)
//
#include <hip/hip_runtime.h>

#define DIM_D 128
#define DIM_2D 256
#define DIM_H 128
#define DIM_O 64

struct EdgeSW { int s; float w; };   // 8B packed

typedef __attribute__((ext_vector_type(8))) short short8v;  // 8 bf16 (4 VGPRs)
typedef __attribute__((ext_vector_type(4))) float f32x4;    // 4 fp32 acc

// ---------------------------------------------------------------------------
// CSR build, both directions fused per stage.
// ---------------------------------------------------------------------------
__global__ __launch_bounds__(256) void hist_both(
    const int* __restrict__ cp_dst, int* __restrict__ cnt_p,
    const int* __restrict__ pc_dst, int* __restrict__ cnt_c,
    int E, int EB)
{
    int b = blockIdx.x;
    const int* dst; int* cnt;
    if (b < EB) { dst = cp_dst; cnt = cnt_p; }
    else        { dst = pc_dst; cnt = cnt_c; b -= EB; }
    int i = b * 256 + threadIdx.x;
    if (i < E) atomicAdd(&cnt[dst[i]], 1);
}

__global__ __launch_bounds__(256) void scan_reduce_both(
    const int* __restrict__ cnt_p, int* __restrict__ bsum_p, int NP, int NBp,
    const int* __restrict__ cnt_c, int* __restrict__ bsum_c, int NC)
{
    int b = blockIdx.x, t = threadIdx.x;
    const int* cnt; int* bsum; int N;
    if (b < NBp) { cnt = cnt_p; bsum = bsum_p; N = NP; }
    else         { cnt = cnt_c; bsum = bsum_c; N = NC; b -= NBp; }
    int base = b * 1024 + t * 4;
    int s = 0;
    #pragma unroll
    for (int k = 0; k < 4; ++k) { int i = base + k; if (i < N) s += cnt[i]; }
    __shared__ int sh[256];
    sh[t] = s; __syncthreads();
    for (int off = 128; off > 0; off >>= 1) {
        if (t < off) sh[t] += sh[t + off];
        __syncthreads();
    }
    if (t == 0) bsum[b] = sh[0];
}

// computes its own bsum prefix (<=98 elements), writes starts, zeros cnt (-> cur)
__global__ __launch_bounds__(256) void scan_write_both(
    int* __restrict__ cnt_p, const int* __restrict__ bsum_p,
    int* __restrict__ starts_p, int NP, int NBp,
    int* __restrict__ cnt_c, const int* __restrict__ bsum_c,
    int* __restrict__ starts_c, int NC)
{
    int b = blockIdx.x, t = threadIdx.x;
    int* cnt; const int* bsum; int* starts; int N;
    if (b < NBp) { cnt = cnt_p; bsum = bsum_p; starts = starts_p; N = NP; }
    else         { cnt = cnt_c; bsum = bsum_c; starts = starts_c; N = NC; b -= NBp; }

    __shared__ int base0;
    if (t == 0) {
        int r = 0;
        for (int j = 0; j < b; ++j) r += bsum[j];
        base0 = r;
    }

    int base = b * 1024 + t * 4;
    int v[4]; int s = 0;
    #pragma unroll
    for (int k = 0; k < 4; ++k) { int i = base + k; v[k] = (i < N) ? cnt[i] : 0; s += v[k]; }
    __shared__ int sh[256];
    sh[t] = s; __syncthreads();
    for (int off = 1; off < 256; off <<= 1) {
        int x = 0;
        if (t >= off) x = sh[t - off];
        __syncthreads();
        if (t >= off) sh[t] += x;
        __syncthreads();
    }
    int run = base0 + (t > 0 ? sh[t - 1] : 0);
    #pragma unroll
    for (int k = 0; k < 4; ++k) {
        int i = base + k;
        if (i < N) {
            starts[i] = run;
            run += v[k];
            cnt[i] = 0;                    // reset -> reused as cursor in place
            if (i == N - 1) starts[N] = run;
        }
    }
}

__global__ __launch_bounds__(256) void place_both(
    const int* __restrict__ cp_edges, const int* __restrict__ starts_p,
    int* __restrict__ cur_p, EdgeSW* __restrict__ csr_cp,
    const int* __restrict__ pc_edges, const int* __restrict__ starts_c,
    int* __restrict__ cur_c, EdgeSW* __restrict__ csr_pc,
    const float* __restrict__ ew, int E, int EB)
{
    int b = blockIdx.x;
    const int* src; const int* dst; const int* starts; int* cur; EdgeSW* csr;
    if (b < EB) { src = cp_edges; dst = cp_edges + E; starts = starts_p; cur = cur_p; csr = csr_cp; }
    else        { src = pc_edges; dst = pc_edges + E; starts = starts_c; cur = cur_c; csr = csr_pc; b -= EB; }
    int i = b * 256 + threadIdx.x;
    if (i >= E) return;
    int d = dst[i];
    int pos = starts[d] + atomicAdd(&cur[d], 1);
    EdgeSW e; e.s = src[i]; e.w = ew[i];
    csr[pos] = e;
}

// ---------------------------------------------------------------------------
// bf16 hi/lo split helpers
// ---------------------------------------------------------------------------
__device__ __forceinline__ void split_bf(float x, unsigned short& hi, unsigned short& lo)
{
    union { float f; unsigned u; } v; v.f = x;
    hi = (unsigned short)(v.u >> 16);
    union { unsigned u; float f; } hv; hv.u = v.u & 0xFFFF0000u;
    union { float f; unsigned u; } rv; rv.f = x - hv.f;
    lo = (unsigned short)(rv.u >> 16);
}

__device__ __forceinline__ void stage_pair(char* hi_base, char* lo_base,
                                           int row, int rowbytes, int posB, float4 v)
{
    int byte = row * rowbytes + (posB ^ ((row & 7) << 4));
    unsigned short h0, h1, h2, h3, l0, l1, l2, l3;
    split_bf(v.x, h0, l0); split_bf(v.y, h1, l1);
    split_bf(v.z, h2, l2); split_bf(v.w, h3, l3);
    uint2 hp, lp;
    hp.x = (unsigned)h0 | ((unsigned)h1 << 16);
    hp.y = (unsigned)h2 | ((unsigned)h3 << 16);
    lp.x = (unsigned)l0 | ((unsigned)l1 << 16);
    lp.y = (unsigned)l2 | ((unsigned)l3 << 16);
    *reinterpret_cast<uint2*>(hi_base + byte) = hp;
    *reinterpret_cast<uint2*>(lo_base + byte) = lp;
}

__device__ __forceinline__ short8v ld_frag(const char* base, int row, int rowbytes, int posB)
{
    int byte = row * rowbytes + (posB ^ ((row & 7) << 4));
    return *reinterpret_cast<const short8v*>(base + byte);
}

// ---------------------------------------------------------------------------
// Weight pre-split: W1/W2 fp32 -> swizzled bf16 hi/lo LDS byte images.
// W1 image: [kc(4)][hi 16KB | lo 16KB], row-major 128B rows, byte = 2c ^ ((r&7)<<4)
// W2 image: [kc2(2)][hi 8KB | lo 8KB],  same row formula (64 rows)
// ---------------------------------------------------------------------------
__global__ __launch_bounds__(256) void presplit_k(
    const float* __restrict__ W1p, const float* __restrict__ W2p,
    const float* __restrict__ W1c, const float* __restrict__ W2c,
    char* __restrict__ w1p_img, char* __restrict__ w2p_img,
    char* __restrict__ w1c_img, char* __restrict__ w2c_img)
{
    int p = blockIdx.x * 256 + threadIdx.x;
    const float* W; char* img; int isW1; int lp;
    if (p < 16384)      { W = W1p; img = w1p_img; isW1 = 1; lp = p; }
    else if (p < 32768) { W = W1c; img = w1c_img; isW1 = 1; lp = p - 16384; }
    else if (p < 36864) { W = W2p; img = w2p_img; isW1 = 0; lp = p - 32768; }
    else if (p < 40960) { W = W2c; img = w2c_img; isW1 = 0; lp = p - 36864; }
    else return;

    int row, q, ncols;
    if (isW1) { row = lp >> 7; q = lp & 127; ncols = 256; }
    else      { row = lp >> 6; q = lp & 63;  ncols = 128; }
    int kc  = q >> 5;
    int cin = (q & 31) * 2;        // in-chunk col of first elem of pair
    float a = W[(size_t)row * ncols + 2 * q];
    float b = W[(size_t)row * ncols + 2 * q + 1];
    unsigned short ah, al, bh, bl;
    split_bf(a, ah, al); split_bf(b, bh, bl);
    int half_sz = isW1 ? 16384 : 8192;
    size_t off = (size_t)kc * 2 * half_sz + (size_t)row * 128
               + ((2 * cin) ^ ((row & 7) << 4));
    *reinterpret_cast<unsigned*>(img + off)           = (unsigned)ah | ((unsigned)bh << 16);
    *reinterpret_cast<unsigned*>(img + off + half_sz) = (unsigned)al | ((unsigned)bl << 16);
}

// ---------------------------------------------------------------------------
// Fused gather + MLP. GEMM1 K-chunks 0,1 stage emb; chunks 2,3 gather the
// message columns directly from the CSR (each wave gathers its own 16 rows).
// ---------------------------------------------------------------------------
#define XS_HI  0
#define XS_LO  8192
#define W1S    16384     // 32 KB: hi 16KB | lo 16KB
#define YS_HI  0
#define YS_LO  16384
#define W2S    32768     // 16 KB: hi 8KB | lo 8KB
#define SMEM_BYTES 49152

__device__ __forceinline__ void mlp_body(int blk,
    const float* __restrict__ emb,
    const EdgeSW* __restrict__ csr, const int* __restrict__ starts,
    const float* __restrict__ src_emb,
    const char* __restrict__ w1img, const char* __restrict__ w2img,
    const float* __restrict__ b1, const float* __restrict__ g1,
    const float* __restrict__ be1,
    const float* __restrict__ b2, const float* __restrict__ g2,
    const float* __restrict__ be2,
    float* __restrict__ out, int N)
{
    __shared__ uint4 smem4[SMEM_BYTES / 16];
    char* smem = reinterpret_cast<char*>(smem4);

    const int t    = threadIdx.x;
    const int lane = t & 63;
    const int wv   = t >> 6;
    const int l15  = lane & 15;
    const int g    = lane >> 4;
    const int r0   = blk * 64;

    f32x4 acc[8];
    #pragma unroll
    for (int nt = 0; nt < 8; ++nt)
        #pragma unroll
        for (int r = 0; r < 4; ++r) acc[nt][r] = 0.f;

    for (int kc = 0; kc < 4; ++kc) {
        if (kc < 2) {
            // stage X chunk from emb (fp32 -> split)
            #pragma unroll
            for (int i = 0; i < 4; ++i) {
                int lin = t + i * 256;
                int row = lin >> 4;
                int c4  = (lin & 15) << 2;
                int node = r0 + row;
                float4 v = make_float4(0.f, 0.f, 0.f, 0.f);
                if (node < N)
                    v = *reinterpret_cast<const float4*>(emb + (size_t)node * DIM_D + kc * 64 + c4);
                stage_pair(smem + XS_HI, smem + XS_LO, row, 128, c4 * 2, v);
            }
        } else {
            // fused gather: msg cols (kc-2)*64 + lane, rows owned by this wave
            int mc = (kc - 2) * 64 + lane;
            for (int rr = 0; rr < 16; ++rr) {
                int row = wv * 16 + rr;
                int node = r0 + row;
                float acc_g = 0.f;
                if (node < N) {
                    int s0 = starts[node], s1 = starts[node + 1];
                    float degw = 0.f;
                    for (int i = s0; i < s1; i += 16) {
                        float vv[16], wk[16];
                        #pragma unroll
                        for (int k = 0; k < 16; ++k) {
                            int idx = i + k;
                            int j = idx < s1 ? idx : s1 - 1;
                            EdgeSW e = csr[j];
                            wk[k] = idx < s1 ? e.w : 0.f;
                            vv[k] = src_emb[(size_t)e.s * DIM_D + mc];
                        }
                        #pragma unroll
                        for (int k = 0; k < 16; ++k) {
                            acc_g += vv[k] * wk[k];
                            degw  += wk[k];
                        }
                    }
                    acc_g *= 1.f / (degw + 1e-8f);
                }
                unsigned short hh, hl;
                split_bf(acc_g, hh, hl);
                int byteoff = row * 128 + ((lane * 2) ^ ((row & 7) << 4));
                *reinterpret_cast<unsigned short*>(smem + XS_HI + byteoff) = hh;
                *reinterpret_cast<unsigned short*>(smem + XS_LO + byteoff) = hl;
            }
        }
        // stage W1 chunk: pure 16B copies from pre-split swizzled image
        {
            const char* src = w1img + (size_t)kc * 32768;
            #pragma unroll
            for (int i = 0; i < 8; ++i) {
                int b = (t + i * 256) * 16;
                *reinterpret_cast<uint4*>(smem + W1S + b) =
                    *reinterpret_cast<const uint4*>(src + b);
            }
        }
        __syncthreads();
        #pragma unroll
        for (int ks = 0; ks < 2; ++ks) {
            int pos = ks * 64 + g * 16;
            short8v a_hi = ld_frag(smem + XS_HI, wv * 16 + l15, 128, pos);
            short8v a_lo = ld_frag(smem + XS_LO, wv * 16 + l15, 128, pos);
            #pragma unroll
            for (int nt = 0; nt < 8; ++nt) {
                short8v b_hi = ld_frag(smem + W1S,         nt * 16 + l15, 128, pos);
                short8v b_lo = ld_frag(smem + W1S + 16384, nt * 16 + l15, 128, pos);
                acc[nt] = __builtin_amdgcn_mfma_f32_16x16x32_bf16(a_hi, b_hi, acc[nt], 0, 0, 0);
                acc[nt] = __builtin_amdgcn_mfma_f32_16x16x32_bf16(a_hi, b_lo, acc[nt], 0, 0, 0);
                acc[nt] = __builtin_amdgcn_mfma_f32_16x16x32_bf16(a_lo, b_hi, acc[nt], 0, 0, 0);
            }
        }
        __syncthreads();
    }

    // ---------------- LN1 + relu (wave-local), write Y to LDS as bf16 pair --
    float b1v[8], g1v[8], be1v[8];
    #pragma unroll
    for (int nt = 0; nt < 8; ++nt) {
        int c = l15 + nt * 16;
        b1v[nt] = b1[c]; g1v[nt] = g1[c]; be1v[nt] = be1[c];
    }
    {
        float s[4] = {0.f, 0.f, 0.f, 0.f}, s2[4] = {0.f, 0.f, 0.f, 0.f};
        #pragma unroll
        for (int nt = 0; nt < 8; ++nt)
            #pragma unroll
            for (int r = 0; r < 4; ++r) {
                float v = acc[nt][r] + b1v[nt];
                acc[nt][r] = v;
                s[r] += v; s2[r] += v * v;
            }
        #pragma unroll
        for (int r = 0; r < 4; ++r) {
            #pragma unroll
            for (int d = 1; d < 16; d <<= 1) {
                s[r]  += __shfl_xor(s[r],  d);
                s2[r] += __shfl_xor(s2[r], d);
            }
            float mu  = s[r] * (1.f / 128.f);
            float var = s2[r] * (1.f / 128.f) - mu * mu;
            float inv = rsqrtf(var + 1e-5f);
            int row = wv * 16 + g * 4 + r;
            #pragma unroll
            for (int nt = 0; nt < 8; ++nt) {
                float h = fmaxf((acc[nt][r] - mu) * inv * g1v[nt] + be1v[nt], 0.f);
                unsigned short hh, hl;
                split_bf(h, hh, hl);
                int k = l15 + nt * 16;
                int byte = row * 256 + ((k * 2) ^ ((row & 7) << 4));
                *reinterpret_cast<unsigned short*>(smem + YS_HI + byte) = hh;
                *reinterpret_cast<unsigned short*>(smem + YS_LO + byte) = hl;
            }
        }
    }

    // ---------------- GEMM2 ----------------
    auto stageW2 = [&](int kc2) {
        const char* src = w2img + (size_t)kc2 * 16384;
        #pragma unroll
        for (int i = 0; i < 4; ++i) {
            int b = (t + i * 256) * 16;
            *reinterpret_cast<uint4*>(smem + W2S + b) =
                *reinterpret_cast<const uint4*>(src + b);
        }
    };
    stageW2(0);
    __syncthreads();

    f32x4 acc2[4];
    #pragma unroll
    for (int nt = 0; nt < 4; ++nt)
        #pragma unroll
        for (int r = 0; r < 4; ++r) acc2[nt][r] = 0.f;

    for (int kc2 = 0; kc2 < 2; ++kc2) {
        if (kc2) { __syncthreads(); stageW2(1); __syncthreads(); }
        #pragma unroll
        for (int ks2 = 0; ks2 < 2; ++ks2) {
            int posY = (kc2 * 2 + ks2) * 64 + g * 16;
            int posW = ks2 * 64 + g * 16;
            short8v a_hi = ld_frag(smem + YS_HI, wv * 16 + l15, 256, posY);
            short8v a_lo = ld_frag(smem + YS_LO, wv * 16 + l15, 256, posY);
            #pragma unroll
            for (int nt = 0; nt < 4; ++nt) {
                short8v b_hi = ld_frag(smem + W2S,        nt * 16 + l15, 128, posW);
                short8v b_lo = ld_frag(smem + W2S + 8192, nt * 16 + l15, 128, posW);
                acc2[nt] = __builtin_amdgcn_mfma_f32_16x16x32_bf16(a_hi, b_hi, acc2[nt], 0, 0, 0);
                acc2[nt] = __builtin_amdgcn_mfma_f32_16x16x32_bf16(a_hi, b_lo, acc2[nt], 0, 0, 0);
                acc2[nt] = __builtin_amdgcn_mfma_f32_16x16x32_bf16(a_lo, b_hi, acc2[nt], 0, 0, 0);
            }
        }
    }

    // ---------------- LN2 (wave-local) + store ----------------
    float b2v[4], g2v[4], be2v[4];
    #pragma unroll
    for (int nt = 0; nt < 4; ++nt) {
        int c = l15 + nt * 16;
        b2v[nt] = b2[c]; g2v[nt] = g2[c]; be2v[nt] = be2[c];
    }
    #pragma unroll
    for (int r = 0; r < 4; ++r) {
        float vv[4];
        float ss = 0.f, ss2 = 0.f;
        #pragma unroll
        for (int nt = 0; nt < 4; ++nt) {
            float v = acc2[nt][r] + b2v[nt];
            vv[nt] = v; ss += v; ss2 += v * v;
        }
        #pragma unroll
        for (int d = 1; d < 16; d <<= 1) {
            ss  += __shfl_xor(ss,  d);
            ss2 += __shfl_xor(ss2, d);
        }
        float mu  = ss * (1.f / 64.f);
        float var = ss2 * (1.f / 64.f) - mu * mu;
        float inv = rsqrtf(var + 1e-5f);
        int node = r0 + wv * 16 + g * 4 + r;
        if (node < N) {
            #pragma unroll
            for (int nt = 0; nt < 4; ++nt)
                out[(size_t)node * DIM_O + l15 + nt * 16] = (vv[nt] - mu) * inv * g2v[nt] + be2v[nt];
        }
    }
}

__global__ __launch_bounds__(256, 3) void gnn_mlp_both(
    const float* __restrict__ p_emb, const float* __restrict__ c_emb,
    const EdgeSW* __restrict__ csr_cp, const int* __restrict__ starts_p,
    const EdgeSW* __restrict__ csr_pc, const int* __restrict__ starts_c,
    const char* __restrict__ w1p_img, const char* __restrict__ w2p_img,
    const char* __restrict__ w1c_img, const char* __restrict__ w2c_img,
    const float* __restrict__ p_b1, const float* __restrict__ p_g1,
    const float* __restrict__ p_be1,
    const float* __restrict__ p_b2, const float* __restrict__ p_g2,
    const float* __restrict__ p_be2,
    const float* __restrict__ c_b1, const float* __restrict__ c_g1,
    const float* __restrict__ c_be1,
    const float* __restrict__ c_b2, const float* __restrict__ c_g2,
    const float* __restrict__ c_be2,
    float* __restrict__ out, int NP, int NC, int NPB)
{
    if ((int)blockIdx.x < NPB) {
        mlp_body(blockIdx.x, p_emb, csr_cp, starts_p, c_emb,
                 w1p_img, w2p_img, p_b1, p_g1, p_be1, p_b2, p_g2, p_be2,
                 out, NP);
    } else {
        mlp_body(blockIdx.x - NPB, c_emb, csr_pc, starts_c, p_emb,
                 w1c_img, w2c_img, c_b1, c_g1, c_be1, c_b2, c_g2, c_be2,
                 out + (size_t)NP * DIM_O, NC);
    }
}

extern "C" void kernel_launch(void* const* d_in, const int* in_sizes, int n_in,
                              void* d_out, int out_size, void* d_ws, size_t ws_size,
                              hipStream_t stream)
{
    const int*   pc_edges = (const int*)d_in[0];   // provider->code (2,E)
    const int*   cp_edges = (const int*)d_in[1];   // code->provider (2,E)
    const float* ew       = (const float*)d_in[2];
    const float* p_emb    = (const float*)d_in[3];
    const float* c_emb    = (const float*)d_in[4];
    const float* p_W1  = (const float*)d_in[5];
    const float* p_b1  = (const float*)d_in[6];
    const float* p_g1  = (const float*)d_in[7];
    const float* p_be1 = (const float*)d_in[8];
    const float* p_W2  = (const float*)d_in[9];
    const float* p_b2  = (const float*)d_in[10];
    const float* p_g2  = (const float*)d_in[11];
    const float* p_be2 = (const float*)d_in[12];
    const float* c_W1  = (const float*)d_in[13];
    const float* c_b1  = (const float*)d_in[14];
    const float* c_g1  = (const float*)d_in[15];
    const float* c_be1 = (const float*)d_in[16];
    const float* c_W2  = (const float*)d_in[17];
    const float* c_b2  = (const float*)d_in[18];
    const float* c_g2  = (const float*)d_in[19];
    const float* c_be2 = (const float*)d_in[20];

    const int E  = in_sizes[2];
    const int NP = in_sizes[3] / DIM_D;
    const int NC = in_sizes[4] / DIM_D;

    // workspace layout
    char* ws = (char*)d_ws;
    size_t off = 0;
    EdgeSW* csr_cp = (EdgeSW*)(ws + off); off += (size_t)E * sizeof(EdgeSW);
    EdgeSW* csr_pc = (EdgeSW*)(ws + off); off += (size_t)E * sizeof(EdgeSW);
    char* w1p_img = ws + off; off += 131072;   // 4 chunks x 32 KB
    char* w1c_img = ws + off; off += 131072;
    char* w2p_img = ws + off; off += 32768;    // 2 chunks x 16 KB
    char* w2c_img = ws + off; off += 32768;
    int* starts_p = (int*)(ws + off); off += (size_t)(NP + 4) * sizeof(int);
    int* starts_c = (int*)(ws + off); off += (size_t)(NC + 4) * sizeof(int);
    int* cnt_p    = (int*)(ws + off); off += (size_t)NP * sizeof(int);
    int* cnt_c    = (int*)(ws + off); off += (size_t)NC * sizeof(int);
    int* bsum_p   = (int*)(ws + off); off += 256 * sizeof(int);
    int* bsum_c   = (int*)(ws + off); off += 256 * sizeof(int);
    (void)ws_size;

    const int EB  = (E + 255) / 256;
    const int NBp = (NP + 1023) / 1024;
    const int NBc = (NC + 1023) / 1024;
    const int NPB = (NP + 63) / 64;
    const int NCB = (NC + 63) / 64;

    presplit_k<<<160, 256, 0, stream>>>(p_W1, p_W2, c_W1, c_W2,
                                        w1p_img, w2p_img, w1c_img, w2c_img);

    hipMemsetAsync(cnt_p, 0, (size_t)(NP + NC) * sizeof(int), stream);

    hist_both<<<2 * EB, 256, 0, stream>>>(cp_edges + E, cnt_p, pc_edges + E, cnt_c, E, EB);

    scan_reduce_both<<<NBp + NBc, 256, 0, stream>>>(cnt_p, bsum_p, NP, NBp,
                                                    cnt_c, bsum_c, NC);

    scan_write_both<<<NBp + NBc, 256, 0, stream>>>(cnt_p, bsum_p, starts_p, NP, NBp,
                                                   cnt_c, bsum_c, starts_c, NC);

    place_both<<<2 * EB, 256, 0, stream>>>(cp_edges, starts_p, cnt_p, csr_cp,
                                           pc_edges, starts_c, cnt_c, csr_pc,
                                           ew, E, EB);

    gnn_mlp_both<<<NPB + NCB, 256, 0, stream>>>(
        p_emb, c_emb, csr_cp, starts_p, csr_pc, starts_c,
        w1p_img, w2p_img, w1c_img, w2c_img,
        p_b1, p_g1, p_be1, p_b2, p_g2, p_be2,
        c_b1, c_g1, c_be1, c_b2, c_g2, c_be2,
        (float*)d_out, NP, NC, NPB);
}

// Round 4
// 543.042 us; speedup vs baseline: 1.4098x; 1.4098x over previous
//
#include <hip/hip_runtime.h>

#define DIM_D 128
#define DIM_2D 256
#define DIM_H 128
#define DIM_O 64

struct EdgeSW { int s; float w; };   // 8B packed

typedef __attribute__((ext_vector_type(8))) short short8v;  // 8 bf16 (4 VGPRs)
typedef __attribute__((ext_vector_type(4))) float f32x4;    // 4 fp32 acc

__device__ __forceinline__ EdgeSW ld_edge_nt(const EdgeSW* p)
{
    unsigned long long v =
        __builtin_nontemporal_load(reinterpret_cast<const unsigned long long*>(p));
    EdgeSW e;
    e.s = (int)(unsigned)(v & 0xFFFFFFFFull);
    union { unsigned u; float f; } w; w.u = (unsigned)(v >> 32); e.w = w.f;
    return e;
}

__device__ __forceinline__ unsigned short f2bf_rne(float f)
{
    union { float f; unsigned u; } v; v.f = f;
    unsigned u = v.u + 0x7FFFu + ((v.u >> 16) & 1u);
    return (unsigned short)(u >> 16);
}

__device__ __forceinline__ float bf2f(unsigned short h)
{
    union { unsigned u; float f; } v; v.u = ((unsigned)h) << 16;
    return v.f;
}

// ---------------------------------------------------------------------------
// CSR build, both directions fused per stage.
// ---------------------------------------------------------------------------
__global__ __launch_bounds__(256) void hist_both(
    const int* __restrict__ cp_dst, int* __restrict__ cnt_p,
    const int* __restrict__ pc_dst, int* __restrict__ cnt_c,
    int E, int EB)
{
    int b = blockIdx.x;
    const int* dst; int* cnt;
    if (b < EB) { dst = cp_dst; cnt = cnt_p; }
    else        { dst = pc_dst; cnt = cnt_c; b -= EB; }
    int i = b * 256 + threadIdx.x;
    if (i < E) atomicAdd(&cnt[dst[i]], 1);
}

__global__ __launch_bounds__(256) void scan_reduce_both(
    const int* __restrict__ cnt_p, int* __restrict__ bsum_p, int NP, int NBp,
    const int* __restrict__ cnt_c, int* __restrict__ bsum_c, int NC)
{
    int b = blockIdx.x, t = threadIdx.x;
    const int* cnt; int* bsum; int N;
    if (b < NBp) { cnt = cnt_p; bsum = bsum_p; N = NP; }
    else         { cnt = cnt_c; bsum = bsum_c; N = NC; b -= NBp; }
    int base = b * 1024 + t * 4;
    int s = 0;
    #pragma unroll
    for (int k = 0; k < 4; ++k) { int i = base + k; if (i < N) s += cnt[i]; }
    __shared__ int sh[256];
    sh[t] = s; __syncthreads();
    for (int off = 128; off > 0; off >>= 1) {
        if (t < off) sh[t] += sh[t + off];
        __syncthreads();
    }
    if (t == 0) bsum[b] = sh[0];
}

// computes its own bsum prefix (<=98 elements), writes starts, zeros cnt (-> cur)
__global__ __launch_bounds__(256) void scan_write_both(
    int* __restrict__ cnt_p, const int* __restrict__ bsum_p,
    int* __restrict__ starts_p, int NP, int NBp,
    int* __restrict__ cnt_c, const int* __restrict__ bsum_c,
    int* __restrict__ starts_c, int NC)
{
    int b = blockIdx.x, t = threadIdx.x;
    int* cnt; const int* bsum; int* starts; int N;
    if (b < NBp) { cnt = cnt_p; bsum = bsum_p; starts = starts_p; N = NP; }
    else         { cnt = cnt_c; bsum = bsum_c; starts = starts_c; N = NC; b -= NBp; }

    __shared__ int base0;
    if (t == 0) {
        int r = 0;
        for (int j = 0; j < b; ++j) r += bsum[j];
        base0 = r;
    }

    int base = b * 1024 + t * 4;
    int v[4]; int s = 0;
    #pragma unroll
    for (int k = 0; k < 4; ++k) { int i = base + k; v[k] = (i < N) ? cnt[i] : 0; s += v[k]; }
    __shared__ int sh[256];
    sh[t] = s; __syncthreads();
    for (int off = 1; off < 256; off <<= 1) {
        int x = 0;
        if (t >= off) x = sh[t - off];
        __syncthreads();
        if (t >= off) sh[t] += x;
        __syncthreads();
    }
    int run = base0 + (t > 0 ? sh[t - 1] : 0);
    #pragma unroll
    for (int k = 0; k < 4; ++k) {
        int i = base + k;
        if (i < N) {
            starts[i] = run;
            run += v[k];
            cnt[i] = 0;                    // reset -> reused as cursor in place
            if (i == N - 1) starts[N] = run;
        }
    }
}

__global__ __launch_bounds__(256) void place_both(
    const int* __restrict__ cp_edges, const int* __restrict__ starts_p,
    int* __restrict__ cur_p, EdgeSW* __restrict__ csr_cp,
    const int* __restrict__ pc_edges, const int* __restrict__ starts_c,
    int* __restrict__ cur_c, EdgeSW* __restrict__ csr_pc,
    const float* __restrict__ ew, int E, int EB)
{
    int b = blockIdx.x;
    const int* src; const int* dst; const int* starts; int* cur; EdgeSW* csr;
    if (b < EB) { src = cp_edges; dst = cp_edges + E; starts = starts_p; cur = cur_p; csr = csr_cp; }
    else        { src = pc_edges; dst = pc_edges + E; starts = starts_c; cur = cur_c; csr = csr_pc; b -= EB; }
    int i = b * 256 + threadIdx.x;
    if (i >= E) return;
    int d = dst[i];
    int pos = starts[d] + atomicAdd(&cur[d], 1);
    EdgeSW e; e.s = src[i]; e.w = ew[i];
    csr[pos] = e;
}

// ---------------------------------------------------------------------------
// Embedding fp32 -> bf16 (RNE) tables for the gather.
// ---------------------------------------------------------------------------
__global__ __launch_bounds__(256) void conv_emb(
    const float* __restrict__ pe, const float* __restrict__ ce,
    unsigned short* __restrict__ pe16, unsigned short* __restrict__ ce16,
    int np8, int nc8)
{
    int i = blockIdx.x * 256 + threadIdx.x;
    const float* src; unsigned short* dst; int g;
    if (i < np8)            { src = pe; dst = pe16; g = i; }
    else if (i < np8 + nc8) { src = ce; dst = ce16; g = i - np8; }
    else return;
    float4 a = *reinterpret_cast<const float4*>(src + (size_t)g * 8);
    float4 b = *reinterpret_cast<const float4*>(src + (size_t)g * 8 + 4);
    uint4 o;
    o.x = (unsigned)f2bf_rne(a.x) | ((unsigned)f2bf_rne(a.y) << 16);
    o.y = (unsigned)f2bf_rne(a.z) | ((unsigned)f2bf_rne(a.w) << 16);
    o.z = (unsigned)f2bf_rne(b.x) | ((unsigned)f2bf_rne(b.y) << 16);
    o.w = (unsigned)f2bf_rne(b.z) | ((unsigned)f2bf_rne(b.w) << 16);
    *reinterpret_cast<uint4*>(dst + (size_t)g * 8) = o;
}

// ---------------------------------------------------------------------------
// Gather, both directions in one launch. Wave per node; 32 lanes cover a row
// (4 bf16 / lane = 8B), two edges processed concurrently across wave halves.
// ---------------------------------------------------------------------------
__global__ __launch_bounds__(256) void gather_both(
    const EdgeSW* __restrict__ csr_cp, const int* __restrict__ starts_p,
    const unsigned short* __restrict__ c_emb16, float* __restrict__ prov_msg, int NP,
    const EdgeSW* __restrict__ csr_pc, const int* __restrict__ starts_c,
    const unsigned short* __restrict__ p_emb16, float* __restrict__ code_msg, int NC)
{
    int wv = (blockIdx.x * 256 + threadIdx.x) >> 6;
    int lane = threadIdx.x & 63;
    const EdgeSW* csr; const int* starts; const unsigned short* emb; float* msg; int n;
    if (wv < NP)           { csr = csr_cp; starts = starts_p; emb = c_emb16; msg = prov_msg; n = wv; }
    else if (wv < NP + NC) { csr = csr_pc; starts = starts_c; emb = p_emb16; msg = code_msg; n = wv - NP; }
    else return;

    const int sub = lane >> 5;          // edge slot within pair
    const int cb  = (lane & 31) * 4;    // column base (4 bf16)

    int s0 = starts[n], s1 = starts[n + 1];
    float4 acc = make_float4(0.f, 0.f, 0.f, 0.f);
    float degw = 0.f;
    int i = s0;
    for (; i + 8 <= s1; i += 8) {
        EdgeSW e0 = ld_edge_nt(csr + i + sub);
        EdgeSW e1 = ld_edge_nt(csr + i + 2 + sub);
        EdgeSW e2 = ld_edge_nt(csr + i + 4 + sub);
        EdgeSW e3 = ld_edge_nt(csr + i + 6 + sub);
        ushort4 v0 = *reinterpret_cast<const ushort4*>(emb + (size_t)e0.s * DIM_D + cb);
        ushort4 v1 = *reinterpret_cast<const ushort4*>(emb + (size_t)e1.s * DIM_D + cb);
        ushort4 v2 = *reinterpret_cast<const ushort4*>(emb + (size_t)e2.s * DIM_D + cb);
        ushort4 v3 = *reinterpret_cast<const ushort4*>(emb + (size_t)e3.s * DIM_D + cb);
        acc.x += bf2f(v0.x) * e0.w + bf2f(v1.x) * e1.w + bf2f(v2.x) * e2.w + bf2f(v3.x) * e3.w;
        acc.y += bf2f(v0.y) * e0.w + bf2f(v1.y) * e1.w + bf2f(v2.y) * e2.w + bf2f(v3.y) * e3.w;
        acc.z += bf2f(v0.z) * e0.w + bf2f(v1.z) * e1.w + bf2f(v2.z) * e2.w + bf2f(v3.z) * e3.w;
        acc.w += bf2f(v0.w) * e0.w + bf2f(v1.w) * e1.w + bf2f(v2.w) * e2.w + bf2f(v3.w) * e3.w;
        degw += e0.w + e1.w + e2.w + e3.w;
    }
    for (; i < s1; i += 2) {
        int idx = i + sub;
        if (idx < s1) {
            EdgeSW e0 = ld_edge_nt(csr + idx);
            ushort4 v0 = *reinterpret_cast<const ushort4*>(emb + (size_t)e0.s * DIM_D + cb);
            acc.x += bf2f(v0.x) * e0.w; acc.y += bf2f(v0.y) * e0.w;
            acc.z += bf2f(v0.z) * e0.w; acc.w += bf2f(v0.w) * e0.w;
            degw += e0.w;
        }
    }
    degw  += __shfl_xor(degw, 32);
    acc.x += __shfl_xor(acc.x, 32);
    acc.y += __shfl_xor(acc.y, 32);
    acc.z += __shfl_xor(acc.z, 32);
    acc.w += __shfl_xor(acc.w, 32);
    float inv = 1.0f / (degw + 1e-8f);
    if (lane < 32)
        *reinterpret_cast<float4*>(msg + (size_t)n * DIM_D + cb) =
            make_float4(acc.x * inv, acc.y * inv, acc.z * inv, acc.w * inv);
}

// ---------------------------------------------------------------------------
// bf16 hi/lo split helpers
// ---------------------------------------------------------------------------
__device__ __forceinline__ void split_bf(float x, unsigned short& hi, unsigned short& lo)
{
    union { float f; unsigned u; } v; v.f = x;
    hi = (unsigned short)(v.u >> 16);
    union { unsigned u; float f; } hv; hv.u = v.u & 0xFFFF0000u;
    union { float f; unsigned u; } rv; rv.f = x - hv.f;
    lo = (unsigned short)(rv.u >> 16);
}

__device__ __forceinline__ void stage_pair(char* hi_base, char* lo_base,
                                           int row, int rowbytes, int posB, float4 v)
{
    int byte = row * rowbytes + (posB ^ ((row & 7) << 4));
    unsigned short h0, h1, h2, h3, l0, l1, l2, l3;
    split_bf(v.x, h0, l0); split_bf(v.y, h1, l1);
    split_bf(v.z, h2, l2); split_bf(v.w, h3, l3);
    uint2 hp, lp;
    hp.x = (unsigned)h0 | ((unsigned)h1 << 16);
    hp.y = (unsigned)h2 | ((unsigned)h3 << 16);
    lp.x = (unsigned)l0 | ((unsigned)l1 << 16);
    lp.y = (unsigned)l2 | ((unsigned)l3 << 16);
    *reinterpret_cast<uint2*>(hi_base + byte) = hp;
    *reinterpret_cast<uint2*>(lo_base + byte) = lp;
}

__device__ __forceinline__ short8v ld_frag(const char* base, int row, int rowbytes, int posB)
{
    int byte = row * rowbytes + (posB ^ ((row & 7) << 4));
    return *reinterpret_cast<const short8v*>(base + byte);
}

// ---------------------------------------------------------------------------
// Weight pre-split: W1/W2 fp32 -> swizzled bf16 hi/lo LDS byte images.
// W1 image: [kc(4)][hi 16KB | lo 16KB]; W2 image: [kc2(2)][hi 8KB | lo 8KB].
// ---------------------------------------------------------------------------
__global__ __launch_bounds__(256) void presplit_k(
    const float* __restrict__ W1p, const float* __restrict__ W2p,
    const float* __restrict__ W1c, const float* __restrict__ W2c,
    char* __restrict__ w1p_img, char* __restrict__ w2p_img,
    char* __restrict__ w1c_img, char* __restrict__ w2c_img)
{
    int p = blockIdx.x * 256 + threadIdx.x;
    const float* W; char* img; int isW1; int lp;
    if (p < 16384)      { W = W1p; img = w1p_img; isW1 = 1; lp = p; }
    else if (p < 32768) { W = W1c; img = w1c_img; isW1 = 1; lp = p - 16384; }
    else if (p < 36864) { W = W2p; img = w2p_img; isW1 = 0; lp = p - 32768; }
    else if (p < 40960) { W = W2c; img = w2c_img; isW1 = 0; lp = p - 36864; }
    else return;

    int row, q, ncols;
    if (isW1) { row = lp >> 7; q = lp & 127; ncols = 256; }
    else      { row = lp >> 6; q = lp & 63;  ncols = 128; }
    int kc  = q >> 5;
    int cin = (q & 31) * 2;        // in-chunk col of first elem of pair
    float a = W[(size_t)row * ncols + 2 * q];
    float b = W[(size_t)row * ncols + 2 * q + 1];
    unsigned short ah, al, bh, bl;
    split_bf(a, ah, al); split_bf(b, bh, bl);
    int half_sz = isW1 ? 16384 : 8192;
    size_t off = (size_t)kc * 2 * half_sz + (size_t)row * 128
               + ((2 * cin) ^ ((row & 7) << 4));
    *reinterpret_cast<unsigned*>(img + off)           = (unsigned)ah | ((unsigned)bh << 16);
    *reinterpret_cast<unsigned*>(img + off + half_sz) = (unsigned)al | ((unsigned)bl << 16);
}

// ---------------------------------------------------------------------------
// Fused MLP via bf16x3 MFMA; weights staged as pure uint4 copies from the
// pre-split swizzled images. X/msg staged fp32 -> split.
// ---------------------------------------------------------------------------
#define XS_HI  0
#define XS_LO  8192
#define W1S    16384     // 32 KB: hi 16KB | lo 16KB
#define YS_HI  0
#define YS_LO  16384
#define W2S    32768     // 16 KB: hi 8KB | lo 8KB
#define SMEM_BYTES 49152

__device__ __forceinline__ void mlp_body(int blk,
    const float* __restrict__ emb, const float* __restrict__ msg,
    const char* __restrict__ w1img, const char* __restrict__ w2img,
    const float* __restrict__ b1, const float* __restrict__ g1,
    const float* __restrict__ be1,
    const float* __restrict__ b2, const float* __restrict__ g2,
    const float* __restrict__ be2,
    float* __restrict__ out, int N)
{
    __shared__ uint4 smem4[SMEM_BYTES / 16];
    char* smem = reinterpret_cast<char*>(smem4);

    const int t    = threadIdx.x;
    const int lane = t & 63;
    const int wv   = t >> 6;
    const int l15  = lane & 15;
    const int g    = lane >> 4;
    const int r0   = blk * 64;

    f32x4 acc[8];
    #pragma unroll
    for (int nt = 0; nt < 8; ++nt)
        #pragma unroll
        for (int r = 0; r < 4; ++r) acc[nt][r] = 0.f;

    for (int kc = 0; kc < 4; ++kc) {
        #pragma unroll
        for (int i = 0; i < 4; ++i) {
            int lin = t + i * 256;
            int row = lin >> 4;
            int c4  = (lin & 15) << 2;
            int node = r0 + row;
            float4 v = make_float4(0.f, 0.f, 0.f, 0.f);
            if (node < N) {
                int col = kc * 64 + c4;
                v = (col < DIM_D)
                  ? *reinterpret_cast<const float4*>(emb + (size_t)node * DIM_D + col)
                  : *reinterpret_cast<const float4*>(msg + (size_t)node * DIM_D + (col - DIM_D));
            }
            stage_pair(smem + XS_HI, smem + XS_LO, row, 128, c4 * 2, v);
        }
        // stage W1 chunk: pure 16B copies from pre-split swizzled image
        {
            const char* src = w1img + (size_t)kc * 32768;
            #pragma unroll
            for (int i = 0; i < 8; ++i) {
                int b = (t + i * 256) * 16;
                *reinterpret_cast<uint4*>(smem + W1S + b) =
                    *reinterpret_cast<const uint4*>(src + b);
            }
        }
        __syncthreads();
        #pragma unroll
        for (int ks = 0; ks < 2; ++ks) {
            int pos = ks * 64 + g * 16;
            short8v a_hi = ld_frag(smem + XS_HI, wv * 16 + l15, 128, pos);
            short8v a_lo = ld_frag(smem + XS_LO, wv * 16 + l15, 128, pos);
            #pragma unroll
            for (int nt = 0; nt < 8; ++nt) {
                short8v b_hi = ld_frag(smem + W1S,         nt * 16 + l15, 128, pos);
                short8v b_lo = ld_frag(smem + W1S + 16384, nt * 16 + l15, 128, pos);
                acc[nt] = __builtin_amdgcn_mfma_f32_16x16x32_bf16(a_hi, b_hi, acc[nt], 0, 0, 0);
                acc[nt] = __builtin_amdgcn_mfma_f32_16x16x32_bf16(a_hi, b_lo, acc[nt], 0, 0, 0);
                acc[nt] = __builtin_amdgcn_mfma_f32_16x16x32_bf16(a_lo, b_hi, acc[nt], 0, 0, 0);
            }
        }
        __syncthreads();
    }

    // ---------------- LN1 + relu (wave-local), write Y to LDS as bf16 pair --
    float b1v[8], g1v[8], be1v[8];
    #pragma unroll
    for (int nt = 0; nt < 8; ++nt) {
        int c = l15 + nt * 16;
        b1v[nt] = b1[c]; g1v[nt] = g1[c]; be1v[nt] = be1[c];
    }
    {
        float s[4] = {0.f, 0.f, 0.f, 0.f}, s2[4] = {0.f, 0.f, 0.f, 0.f};
        #pragma unroll
        for (int nt = 0; nt < 8; ++nt)
            #pragma unroll
            for (int r = 0; r < 4; ++r) {
                float v = acc[nt][r] + b1v[nt];
                acc[nt][r] = v;
                s[r] += v; s2[r] += v * v;
            }
        #pragma unroll
        for (int r = 0; r < 4; ++r) {
            #pragma unroll
            for (int d = 1; d < 16; d <<= 1) {
                s[r]  += __shfl_xor(s[r],  d);
                s2[r] += __shfl_xor(s2[r], d);
            }
            float mu  = s[r] * (1.f / 128.f);
            float var = s2[r] * (1.f / 128.f) - mu * mu;
            float inv = rsqrtf(var + 1e-5f);
            int row = wv * 16 + g * 4 + r;
            #pragma unroll
            for (int nt = 0; nt < 8; ++nt) {
                float h = fmaxf((acc[nt][r] - mu) * inv * g1v[nt] + be1v[nt], 0.f);
                unsigned short hh, hl;
                split_bf(h, hh, hl);
                int k = l15 + nt * 16;
                int byte = row * 256 + ((k * 2) ^ ((row & 7) << 4));
                *reinterpret_cast<unsigned short*>(smem + YS_HI + byte) = hh;
                *reinterpret_cast<unsigned short*>(smem + YS_LO + byte) = hl;
            }
        }
    }

    // ---------------- GEMM2 ----------------
    auto stageW2 = [&](int kc2) {
        const char* src = w2img + (size_t)kc2 * 16384;
        #pragma unroll
        for (int i = 0; i < 4; ++i) {
            int b = (t + i * 256) * 16;
            *reinterpret_cast<uint4*>(smem + W2S + b) =
                *reinterpret_cast<const uint4*>(src + b);
        }
    };
    stageW2(0);
    __syncthreads();

    f32x4 acc2[4];
    #pragma unroll
    for (int nt = 0; nt < 4; ++nt)
        #pragma unroll
        for (int r = 0; r < 4; ++r) acc2[nt][r] = 0.f;

    for (int kc2 = 0; kc2 < 2; ++kc2) {
        if (kc2) { __syncthreads(); stageW2(1); __syncthreads(); }
        #pragma unroll
        for (int ks2 = 0; ks2 < 2; ++ks2) {
            int posY = (kc2 * 2 + ks2) * 64 + g * 16;
            int posW = ks2 * 64 + g * 16;
            short8v a_hi = ld_frag(smem + YS_HI, wv * 16 + l15, 256, posY);
            short8v a_lo = ld_frag(smem + YS_LO, wv * 16 + l15, 256, posY);
            #pragma unroll
            for (int nt = 0; nt < 4; ++nt) {
                short8v b_hi = ld_frag(smem + W2S,        nt * 16 + l15, 128, posW);
                short8v b_lo = ld_frag(smem + W2S + 8192, nt * 16 + l15, 128, posW);
                acc2[nt] = __builtin_amdgcn_mfma_f32_16x16x32_bf16(a_hi, b_hi, acc2[nt], 0, 0, 0);
                acc2[nt] = __builtin_amdgcn_mfma_f32_16x16x32_bf16(a_hi, b_lo, acc2[nt], 0, 0, 0);
                acc2[nt] = __builtin_amdgcn_mfma_f32_16x16x32_bf16(a_lo, b_hi, acc2[nt], 0, 0, 0);
            }
        }
    }

    // ---------------- LN2 (wave-local) + store ----------------
    float b2v[4], g2v[4], be2v[4];
    #pragma unroll
    for (int nt = 0; nt < 4; ++nt) {
        int c = l15 + nt * 16;
        b2v[nt] = b2[c]; g2v[nt] = g2[c]; be2v[nt] = be2[c];
    }
    #pragma unroll
    for (int r = 0; r < 4; ++r) {
        float vv[4];
        float ss = 0.f, ss2 = 0.f;
        #pragma unroll
        for (int nt = 0; nt < 4; ++nt) {
            float v = acc2[nt][r] + b2v[nt];
            vv[nt] = v; ss += v; ss2 += v * v;
        }
        #pragma unroll
        for (int d = 1; d < 16; d <<= 1) {
            ss  += __shfl_xor(ss,  d);
            ss2 += __shfl_xor(ss2, d);
        }
        float mu  = ss * (1.f / 64.f);
        float var = ss2 * (1.f / 64.f) - mu * mu;
        float inv = rsqrtf(var + 1e-5f);
        int node = r0 + wv * 16 + g * 4 + r;
        if (node < N) {
            #pragma unroll
            for (int nt = 0; nt < 4; ++nt)
                out[(size_t)node * DIM_O + l15 + nt * 16] = (vv[nt] - mu) * inv * g2v[nt] + be2v[nt];
        }
    }
}

__global__ __launch_bounds__(256, 3) void gnn_mlp_both(
    const float* __restrict__ p_emb, const float* __restrict__ prov_msg,
    const float* __restrict__ c_emb, const float* __restrict__ code_msg,
    const char* __restrict__ w1p_img, const char* __restrict__ w2p_img,
    const char* __restrict__ w1c_img, const char* __restrict__ w2c_img,
    const float* __restrict__ p_b1, const float* __restrict__ p_g1,
    const float* __restrict__ p_be1,
    const float* __restrict__ p_b2, const float* __restrict__ p_g2,
    const float* __restrict__ p_be2,
    const float* __restrict__ c_b1, const float* __restrict__ c_g1,
    const float* __restrict__ c_be1,
    const float* __restrict__ c_b2, const float* __restrict__ c_g2,
    const float* __restrict__ c_be2,
    float* __restrict__ out, int NP, int NC, int NPB)
{
    if ((int)blockIdx.x < NPB) {
        mlp_body(blockIdx.x, p_emb, prov_msg, w1p_img, w2p_img,
                 p_b1, p_g1, p_be1, p_b2, p_g2, p_be2, out, NP);
    } else {
        mlp_body(blockIdx.x - NPB, c_emb, code_msg, w1c_img, w2c_img,
                 c_b1, c_g1, c_be1, c_b2, c_g2, c_be2,
                 out + (size_t)NP * DIM_O, NC);
    }
}

extern "C" void kernel_launch(void* const* d_in, const int* in_sizes, int n_in,
                              void* d_out, int out_size, void* d_ws, size_t ws_size,
                              hipStream_t stream)
{
    const int*   pc_edges = (const int*)d_in[0];   // provider->code (2,E)
    const int*   cp_edges = (const int*)d_in[1];   // code->provider (2,E)
    const float* ew       = (const float*)d_in[2];
    const float* p_emb    = (const float*)d_in[3];
    const float* c_emb    = (const float*)d_in[4];
    const float* p_W1  = (const float*)d_in[5];
    const float* p_b1  = (const float*)d_in[6];
    const float* p_g1  = (const float*)d_in[7];
    const float* p_be1 = (const float*)d_in[8];
    const float* p_W2  = (const float*)d_in[9];
    const float* p_b2  = (const float*)d_in[10];
    const float* p_g2  = (const float*)d_in[11];
    const float* p_be2 = (const float*)d_in[12];
    const float* c_W1  = (const float*)d_in[13];
    const float* c_b1  = (const float*)d_in[14];
    const float* c_g1  = (const float*)d_in[15];
    const float* c_be1 = (const float*)d_in[16];
    const float* c_W2  = (const float*)d_in[17];
    const float* c_b2  = (const float*)d_in[18];
    const float* c_g2  = (const float*)d_in[19];
    const float* c_be2 = (const float*)d_in[20];

    const int E  = in_sizes[2];
    const int NP = in_sizes[3] / DIM_D;
    const int NC = in_sizes[4] / DIM_D;

    // workspace layout
    char* ws = (char*)d_ws;
    size_t off = 0;
    float*  prov_msg = (float*)(ws + off); off += (size_t)NP * DIM_D * sizeof(float);
    float*  code_msg = (float*)(ws + off); off += (size_t)NC * DIM_D * sizeof(float);
    EdgeSW* csr_cp   = (EdgeSW*)(ws + off); off += (size_t)E * sizeof(EdgeSW);
    EdgeSW* csr_pc   = (EdgeSW*)(ws + off); off += (size_t)E * sizeof(EdgeSW);
    unsigned short* p_emb16 = (unsigned short*)(ws + off); off += (size_t)NP * DIM_D * 2;
    unsigned short* c_emb16 = (unsigned short*)(ws + off); off += (size_t)NC * DIM_D * 2;
    char* w1p_img = ws + off; off += 131072;   // 4 chunks x 32 KB
    char* w1c_img = ws + off; off += 131072;
    char* w2p_img = ws + off; off += 32768;    // 2 chunks x 16 KB
    char* w2c_img = ws + off; off += 32768;
    int* starts_p = (int*)(ws + off); off += (size_t)(NP + 4) * sizeof(int);
    int* starts_c = (int*)(ws + off); off += (size_t)(NC + 4) * sizeof(int);
    int* cnt_p    = (int*)(ws + off); off += (size_t)NP * sizeof(int);
    int* cnt_c    = (int*)(ws + off); off += (size_t)NC * sizeof(int);
    int* bsum_p   = (int*)(ws + off); off += 256 * sizeof(int);
    int* bsum_c   = (int*)(ws + off); off += 256 * sizeof(int);
    (void)ws_size;

    const int EB  = (E + 255) / 256;
    const int NBp = (NP + 1023) / 1024;
    const int NBc = (NC + 1023) / 1024;
    const int NPB = (NP + 63) / 64;
    const int NCB = (NC + 63) / 64;
    const int np8 = NP * (DIM_D / 8);
    const int nc8 = NC * (DIM_D / 8);

    hipMemsetAsync(cnt_p, 0, (size_t)(NP + NC) * sizeof(int), stream);

    presplit_k<<<160, 256, 0, stream>>>(p_W1, p_W2, c_W1, c_W2,
                                        w1p_img, w2p_img, w1c_img, w2c_img);

    conv_emb<<<(np8 + nc8 + 255) / 256, 256, 0, stream>>>(p_emb, c_emb,
                                                          p_emb16, c_emb16,
                                                          np8, nc8);

    hist_both<<<2 * EB, 256, 0, stream>>>(cp_edges + E, cnt_p, pc_edges + E, cnt_c, E, EB);

    scan_reduce_both<<<NBp + NBc, 256, 0, stream>>>(cnt_p, bsum_p, NP, NBp,
                                                    cnt_c, bsum_c, NC);

    scan_write_both<<<NBp + NBc, 256, 0, stream>>>(cnt_p, bsum_p, starts_p, NP, NBp,
                                                   cnt_c, bsum_c, starts_c, NC);

    place_both<<<2 * EB, 256, 0, stream>>>(cp_edges, starts_p, cnt_p, csr_cp,
                                           pc_edges, starts_c, cnt_c, csr_pc,
                                           ew, E, EB);

    gather_both<<<(NP + NC + 3) / 4, 256, 0, stream>>>(
        csr_cp, starts_p, c_emb16, prov_msg, NP,
        csr_pc, starts_c, p_emb16, code_msg, NC);

    gnn_mlp_both<<<NPB + NCB, 256, 0, stream>>>(
        p_emb, prov_msg, c_emb, code_msg,
        w1p_img, w2p_img, w1c_img, w2c_img,
        p_b1, p_g1, p_be1, p_b2, p_g2, p_be2,
        c_b1, c_g1, c_be1, c_b2, c_g2, c_be2,
        (float*)d_out, NP, NC, NPB);
}